// Round 8
// baseline (10325.427 us; speedup 1.0000x reference)
//
#include <hip/hip_runtime.h>
#include <math.h>

typedef _Float16 h2_t __attribute__((ext_vector_type(2)));

#define U_ 256
#define NN 128
#define MM 64
#define OUT_ 8
#define CLIPV 20.0f
#define IN_DIM_ 9
#define HH 2
#define PP 268
#define PPAD 272
#define B_ 128
#define T_ 130
#define TSTART 65
#define CTRL_ 73

// half2-element counts (same layout as R6 prep)
#define WX2_H2 (40*1024)      // 40 K-pairs x 1024 cols (unit-major)
#define WH2_H2 (128*1024)     // 128 K-pairs x 1024 cols
#define WP2_H2 (128*PPAD)     // 128 K-pairs x 272 cols
// byte offsets in ws
#define WX2_OFF 0
#define WH2_OFF (WX2_H2*4)
#define WP2_OFF (WH2_OFF + WH2_H2*4)
#define BLP_OFF (WP2_OFF + WP2_H2*4)
#define BPP_OFF (BLP_OFF + 1024*4)
#define PREP_TOT (WX2_H2 + WH2_H2 + WP2_H2 + 1024 + PPAD)

#define WPTILE 17408          // 16 K-pairs x 272 cols x 4B

__device__ __forceinline__ float sigf(float x){ return 1.0f/(1.0f+__expf(-x)); }
__device__ __forceinline__ float splus(float x){ return log1pf(__expf(x)); }
__device__ __forceinline__ float clipf(float x){ return fminf(fmaxf(x,-CLIPV),CLIPV); }

#if defined(__has_builtin)
#if __has_builtin(__builtin_amdgcn_fdot2)
#define DOT2(a,b,c) __builtin_amdgcn_fdot2((a),(b),(c),false)
#endif
#endif
#ifndef DOT2
#define DOT2(a,b,c) fmaf((float)(a).x,(float)(b).x, fmaf((float)(a).y,(float)(b).y,(c)))
#endif

__device__ __forceinline__ void dma16(const char* g, const char* l){
    __builtin_amdgcn_global_load_lds(
        (const __attribute__((address_space(1))) void*)g,
        (__attribute__((address_space(3))) void*)(char*)l, 16, 0, 0);
}

__global__ void prep_kernel(const float* __restrict__ W_x, const float* __restrict__ W_h,
                            const float* __restrict__ W_p, const float* __restrict__ b_lstm,
                            const float* __restrict__ b_p,
                            h2_t* __restrict__ wx2, h2_t* __restrict__ wh2,
                            h2_t* __restrict__ wp2,
                            float* __restrict__ blp, float* __restrict__ bpp)
{
    for (int idx = blockIdx.x*blockDim.x + threadIdx.x; idx < PREP_TOT; idx += gridDim.x*blockDim.x){
        if (idx < WX2_H2){
            // ctrl order: [r(0..63) -> W_x rows 9+i ; x(64..72) -> rows i-64 ; pad]
            int p = idx>>10, jn = idx&1023, u = jn>>2, k = jn&3, c = k*256+u;
            int i0 = 2*p, i1 = 2*p+1;
            float f0 = (i0<64) ? W_x[(9+i0)*1024+c] : (i0<CTRL_ ? W_x[(i0-64)*1024+c] : 0.f);
            float f1 = (i1<64) ? W_x[(9+i1)*1024+c] : (i1<CTRL_ ? W_x[(i1-64)*1024+c] : 0.f);
            h2_t v; v.x = (_Float16)f0; v.y = (_Float16)f1;
            wx2[idx] = v;
        } else if (idx < WX2_H2 + WH2_H2){
            int e = idx - WX2_H2;
            int p = e>>10, jn = e&1023, u = jn>>2, k = jn&3, c = k*256+u;
            h2_t v; v.x = (_Float16)W_h[(2*p)*1024+c]; v.y = (_Float16)W_h[(2*p+1)*1024+c];
            wh2[e] = v;
        } else if (idx < WX2_H2 + WH2_H2 + WP2_H2){
            int e = idx - WX2_H2 - WH2_H2;
            int p = e / PPAD, j = e - p*PPAD;
            float f0 = (j<PP) ? W_p[(2*p)*PP + j] : 0.f;
            float f1 = (j<PP) ? W_p[(2*p+1)*PP + j] : 0.f;
            h2_t v; v.x = (_Float16)f0; v.y = (_Float16)f1;
            wp2[e] = v;
        } else if (idx < WX2_H2 + WH2_H2 + WP2_H2 + 1024){
            int jn = idx - (WX2_H2 + WH2_H2 + WP2_H2);
            int u = jn>>2, k = jn&3;
            blp[jn] = b_lstm[k*256 + u];
        } else {
            int j = idx - (WX2_H2 + WH2_H2 + WP2_H2 + 1024);
            bpp[j] = (j < PP) ? b_p[j] : 0.0f;
        }
    }
}

__global__ __launch_bounds__(1024,1) void ntm_kernel(
    const float* __restrict__ inputs,
    const float* __restrict__ W_o, const float* __restrict__ b_o,
    const float* __restrict__ r0, const float* __restrict__ w0,
    const h2_t* __restrict__ wx2, const h2_t* __restrict__ wh2,
    const h2_t* __restrict__ wp2,
    const float* __restrict__ blp, const float* __restrict__ bpp,
    float* __restrict__ out)
{
    const int b = blockIdx.x;
    const int t = threadIdx.x;
    const int wv = t >> 6, ln = t & 63;

    __shared__ uint4 stg[2][2048];     // 2 x 32KB staging
    __shared__ float Mem[NN][MM+1];
    __shared__ float hbuf[U_], cbuf[U_];
    __shared__ float4 gates4[U_];      // 1024 gates, unit-major
    __shared__ float gpart[4*U_];      // h@W_h + blp, one step ahead
    __shared__ float blpS[4*U_];
    __shared__ h2_t  xr2[40];          // packed ctrl: [r(32 pairs); x(5 pairs); pad]
    __shared__ h2_t  hb2[U_/2];
    __shared__ float jpart[OUT_];
    __shared__ float kv[HH][MM];
    __shared__ float ebuf[MM], abuf[MM];
    __shared__ float prmS[12];
    __shared__ float scal[12];
    __shared__ float innr[HH][NN];
    __shared__ float Mn[NN];
    __shared__ float wgs[HH][NN];
    __shared__ float wtab[HH][NN];
    __shared__ float rpart[16][MM];

    _Float16* hbh = (_Float16*)hb2;
    float* gatesF = (float*)gates4;

    const char* wxB = (const char*)wx2;
    const char* whB = (const char*)wh2;
    const char* wpB = (const char*)wp2;

    // issue DMA for tile seq s (0-4 wx, 5-20 wh, 21-28 wp) into buffer p
    auto issue = [&](int s, int p){
        const char* lb = ((const char*)&stg[0][0]) + p*32768;
        if (s < 21){
            const char* gt = (s < 5) ? (wxB + s*32768) : (whB + (s-5)*32768);
            dma16(gt + t*16,          lb + wv*1024);
            dma16(gt + 16384 + t*16,  lb + 16384 + wv*1024);
        } else {
            const char* gt = wpB + (s-21)*WPTILE;
            dma16(gt + t*16, lb + wv*1024);
            if (t < 88) dma16(gt + 16384 + t*16, lb + 16384 + wv*1024);
        }
    };

    // ---- init ----
    for (int idx=t; idx<NN*MM; idx+=1024){ Mem[idx>>6][idx&63] = 1e-6f; }
    blpS[t] = blp[t];
    gpart[t] = blpS[t];
    if (t < NN) Mn[t] = sqrtf((float)MM * 1e-6f * 1e-6f);
    if (t < U_){ hbuf[t]=0.f; cbuf[t]=0.f; }
    if (t < U_/2){ h2_t z; z.x=(_Float16)0.f; z.y=(_Float16)0.f; hb2[t]=z; }
    if (t >= 256 && t < 296){
        int p = t-256;
        h2_t v;
        if (p < 32){ v.x = (_Float16)tanhf(r0[2*p]); v.y = (_Float16)tanhf(r0[2*p+1]); }
        else if (p < 37){
            int e0 = 2*(p-32), e1 = e0+1;
            float f0 = (e0<IN_DIM_) ? inputs[b*T_*IN_DIM_ + e0] : 0.f;
            float f1 = (e1<IN_DIM_) ? inputs[b*T_*IN_DIM_ + e1] : 0.f;
            v.x = (_Float16)f0; v.y = (_Float16)f1;
        } else { v.x=(_Float16)0.f; v.y=(_Float16)0.f; }
        xr2[p] = v;
    }
    if (t >= 128 && t < 256){  // wtab = softmax(w0)
        int h = (t-128)>>6, l = t&63;
        float v0 = w0[h*NN + l], v1 = w0[h*NN + l + 64];
        float mx = fmaxf(v0,v1);
        for (int off=32; off>=1; off>>=1) mx = fmaxf(mx, __shfl_xor(mx, off));
        float e0 = __expf(v0-mx), e1 = __expf(v1-mx);
        float s = e0+e1;
        for (int off=32; off>=1; off>>=1) s += __shfl_xor(s, off);
        wtab[h][l] = e0/s; wtab[h][l+64] = e1/s;
    }
    int par = 0;
    issue(0, par);            // prefetch wx tile 0
    __syncthreads();          // pre-barrier drain completes it

    for (int step=0; step<T_; ++step){
        // ---- B: gates GEMV, staged wx tiles ----
        float accX = 0.f;
        for (int c=0; c<5; ++c){
            issue(c+1, par^1);                       // X1..X4 then H0
            const h2_t* Bt = (const h2_t*)&stg[par][0];
            #pragma unroll
            for (int p=0; p<8; ++p)
                accX = DOT2(xr2[8*c+p], Bt[p*1024+t], accX);
            if (c==4) gatesF[t] = accX + gpart[t];   // gpart includes bias
            __syncthreads(); par ^= 1;
        }
        // ---- LSTM (unit u = t) ----
        if (t < U_){
            float4 g4 = gates4[t];
            float c = sigf(g4.y)*cbuf[t] + sigf(g4.x)*tanhf(g4.z);
            cbuf[t] = c;
            float h = sigf(g4.w)*tanhf(c);
            hbuf[t] = h; hbh[t] = (_Float16)h;
        }
        __syncthreads();

        // ---- gpart: h@W_h, staged wh tiles ----
        float accG = 0.f;
        for (int c=0; c<16; ++c){
            issue((c<15) ? (6+c) : 21, par^1);       // H1..H15 then P0
            const h2_t* Bt = (const h2_t*)&stg[par][0];
            #pragma unroll
            for (int p=0; p<8; ++p)
                accG = DOT2(hb2[8*c+p], Bt[p*1024+t], accG);
            if (c==15) gpart[t] = accG + blpS[t];
            __syncthreads(); par ^= 1;
        }

        // ---- params: h@W_p, staged wp tiles (t<544) + aux on idle threads ----
        float accP = 0.f;
        const int colP = t>>1, qP = t&1;
        for (int c=0; c<8; ++c){
            if (c<7) issue(22+c, par^1);             // P1..P7
            if (t < 544){
                const h2_t* Bt = (const h2_t*)&stg[par][0];
                #pragma unroll
                for (int i=0; i<8; ++i)
                    accP = DOT2(hb2[16*c + 8*qP + i], Bt[(8*qP+i)*272 + colP], accP);
            } else if (c==0 && t < 800){
                const int idx = t-544, n = idx>>1, m0 = (idx&1)*32;
                float s = 0.f;
                #pragma unroll 8
                for (int m=m0; m<m0+32; ++m){ float v=Mem[n][m]; s=fmaf(v,v,s); }
                s += __shfl_xor(s,1);
                if ((idx&1)==0) Mn[n] = sqrtf(s);
            } else if (c==1 && t >= 896){
                const int o = (t-896)>>4, l16 = t&15;
                float s = 0.f;
                #pragma unroll
                for (int j=0; j<16; ++j){
                    const int i = l16 + (j<<4);
                    s = fmaf(hbuf[i], W_o[i*OUT_ + o], s);
                }
                s += __shfl_xor(s,1); s += __shfl_xor(s,2);
                s += __shfl_xor(s,4); s += __shfl_xor(s,8);
                if (l16==0) jpart[o] = s;
            } else if (c==2 && t >= 800 && t < 805){
                if (step+1 < T_){
                    const int p = t-800;
                    const int e0 = 2*p, e1 = e0+1;
                    const float* xin = inputs + (b*T_ + step+1)*IN_DIM_;
                    h2_t v;
                    v.x = (_Float16)((e0<IN_DIM_) ? xin[e0] : 0.f);
                    v.y = (_Float16)((e1<IN_DIM_) ? xin[e1] : 0.f);
                    xr2[32+p] = v;
                }
            }
            __syncthreads(); par ^= 1;
        }
        // decode params
        if (t < 544){
            float a = accP + __shfl_xor(accP, 1);
            if (qP==0){
                const int j = colP;
                float p = clipf(a + bpp[j]);
                if (j < 64) kv[0][j] = tanhf(p);
                else if (j < 70) prmS[j-64] = p;
                else if (j < 134) kv[1][j-70] = tanhf(p);
                else if (j < 140) prmS[6 + (j-134)] = p;
                else if (j < 204) ebuf[j-140] = sigf(p);
                else if (j < 268) abuf[j-204] = tanhf(p);
            }
        }
        __syncthreads();

        // ---- F: inner products + scal decode ----
        {
            const int h = t>>9, n = (t>>2)&127, q = t&3, m0 = q*16;
            float s = 0.f;
            #pragma unroll 8
            for (int m=m0; m<m0+16; ++m) s = fmaf(kv[h][m], Mem[n][m], s);
            s += __shfl_xor(s,1); s += __shfl_xor(s,2);
            if (q==0) innr[h][n] = s;
        }
        if (t < 2){
            const int h = t;
            const float* ps = prmS + 6*h;
            scal[h]   = splus(ps[0]);
            scal[2+h] = sigf(ps[1]);
            float p0=ps[2], p1=ps[3], p2=ps[4];
            float mx = fmaxf(p0, fmaxf(p1, p2));
            float e0=__expf(p0-mx), e1=__expf(p1-mx), e2=__expf(p2-mx);
            float s = e0+e1+e2;
            scal[6+3*h]=e0/s; scal[7+3*h]=e1/s; scal[8+3*h]=e2/s;
            scal[4+h] = 1.f + splus(ps[5]);
        }
        __syncthreads();

        // ---- G: key norm + content softmax + interp + shift + sharpen ----
        if (t < 128){
            const int h = t>>6, l = ln;
            float kvl = kv[h][l];
            float kn2 = kvl*kvl;
            for (int off=32; off>=1; off>>=1) kn2 += __shfl_xor(kn2, off);
            float kn = sqrtf(kn2);
            float beta = scal[h], g = scal[2+h];
            float bk0 = beta * innr[h][l]   /(kn*Mn[l]   +1e-8f);
            float bk1 = beta * innr[h][l+64]/(kn*Mn[l+64]+1e-8f);
            float mx = fmaxf(bk0,bk1);
            for (int off=32; off>=1; off>>=1) mx = fmaxf(mx, __shfl_xor(mx, off));
            float e0=__expf(bk0-mx), e1=__expf(bk1-mx);
            float s=e0+e1;
            for (int off=32; off>=1; off>>=1) s += __shfl_xor(s, off);
            float wc0=e0/s, wc1=e1/s;
            wgs[h][l]    = g*wc0 + (1.f-g)*wtab[h][l];
            wgs[h][l+64] = g*wc1 + (1.f-g)*wtab[h][l+64];
            float gamma = scal[4+h];
            float s0=scal[6+3*h], s1=scal[7+3*h], s2=scal[8+3*h];
            const int n0=l, n1=l+64;
            float wt0 = s0*wgs[h][(n0+1)&127] + s1*wgs[h][n0] + s2*wgs[h][(n0+127)&127];
            float wt1 = s0*wgs[h][(n1+1)&127] + s1*wgs[h][n1] + s2*wgs[h][(n1+127)&127];
            float wp0 = __powf(wt0, gamma), wp1 = __powf(wt1, gamma);
            float ss = wp0+wp1;
            for (int off=32; off>=1; off>>=1) ss += __shfl_xor(ss, off);
            float inv = 1.0f/(ss+1e-8f);
            wtab[h][n0] = wp0*inv; wtab[h][n1] = wp1*inv;
        }
        __syncthreads();

        // ---- H: memory write + fused read-head partials ----
        {
            const float el = ebuf[ln], al = abuf[ln];
            const int n0 = wv*8;
            float racc = 0.f;
            #pragma unroll
            for (int k=0; k<8; ++k){
                const int n = n0+k;
                float ww = wtab[1][n];
                float wr = wtab[0][n];
                float v = Mem[n][ln]*(1.0f - ww*el) + ww*al;
                Mem[n][ln] = v;
                racc = fmaf(wr, v, racc);
            }
            rpart[wv][ln] = racc;
        }
        __syncthreads();

        // ---- J: r finalize + output ; prefetch next step's wx tile 0 ----
        issue(0, par);
        if (t < 512){
            const int o = wv;
            float rm = 0.f;
            #pragma unroll
            for (int k=0; k<16; ++k) rm += rpart[k][ln];
            float s = rm * W_o[(U_+ln)*OUT_ + o];
            for (int off=32; off>=1; off>>=1) s += __shfl_xor(s, off);
            if (ln==0 && step>=TSTART){
                float logit = clipf(s + jpart[o] + b_o[o]);
                out[((b*(T_-TSTART)) + (step-TSTART))*OUT_ + o] = sigf(logit);
            }
        } else if (t < 576){
            float rm = 0.f;
            #pragma unroll
            for (int k=0; k<16; ++k) rm += rpart[k][ln];
            float other = __shfl_xor(rm, 1);
            if ((ln&1)==0){
                h2_t v; v.x = (_Float16)rm; v.y = (_Float16)other;
                xr2[ln>>1] = v;
            }
        }
        __syncthreads();
    }
}

extern "C" void kernel_launch(void* const* d_in, const int* in_sizes, int n_in,
                              void* d_out, int out_size, void* d_ws, size_t ws_size,
                              hipStream_t stream) {
    const float* inputs = (const float*)d_in[0];
    const float* W_x    = (const float*)d_in[1];
    const float* W_h    = (const float*)d_in[2];
    const float* b_lstm = (const float*)d_in[3];
    const float* W_p    = (const float*)d_in[4];
    const float* b_p    = (const float*)d_in[5];
    const float* W_o    = (const float*)d_in[6];
    const float* b_o    = (const float*)d_in[7];
    const float* r0     = (const float*)d_in[8];
    const float* w0     = (const float*)d_in[9];
    float* out = (float*)d_out;

    char* ws = (char*)d_ws;
    h2_t* wx2 = (h2_t*)(ws + WX2_OFF);
    h2_t* wh2 = (h2_t*)(ws + WH2_OFF);
    h2_t* wp2 = (h2_t*)(ws + WP2_OFF);
    float* blp = (float*)(ws + BLP_OFF);
    float* bpp = (float*)(ws + BPP_OFF);

    prep_kernel<<<512, 256, 0, stream>>>(W_x, W_h, W_p, b_lstm, b_p, wx2, wh2, wp2, blp, bpp);
    ntm_kernel<<<B_, 1024, 0, stream>>>(inputs, W_o, b_o, r0, w0, wx2, wh2, wp2, blp, bpp, out);
}

// Round 9
// 4719.054 us; speedup vs baseline: 2.1880x; 2.1880x over previous
//
#include <hip/hip_runtime.h>
#include <math.h>

typedef _Float16 h2_t __attribute__((ext_vector_type(2)));

#define U_ 256
#define NN 128
#define MM 64
#define OUT_ 8
#define CLIPV 20.0f
#define IN_DIM_ 9
#define HH 2
#define PP 268
#define PPAD 272
#define B_ 128
#define T_ 130
#define TSTART 65
#define CTRL_ 73

// per-thread-contiguous layouts (h2 = fp16 pair = 4B)
#define WXT_H2 (1024*40)     // thread t: 40 K-pairs contiguous (col = unit-major perm)
#define WHT_H2 (1024*128)    // thread t: 128 K-pairs contiguous
#define WPT_H2 (544*64)      // thread tt: 64 K-pairs (col=tt>>1, Khalf=tt&1)
#define WXT_OFF 0
#define WHT_OFF (WXT_H2*4)
#define WPT_OFF (WHT_OFF + WHT_H2*4)
#define BLP_OFF (WPT_OFF + WPT_H2*4)
#define BPP_OFF (BLP_OFF + 1024*4)
#define PREP_TOT (WXT_H2 + WHT_H2 + WPT_H2 + 1024 + PPAD)

__device__ __forceinline__ float sigf(float x){ return 1.0f/(1.0f+__expf(-x)); }
__device__ __forceinline__ float splus(float x){ return log1pf(__expf(x)); }
__device__ __forceinline__ float clipf(float x){ return fminf(fmaxf(x,-CLIPV),CLIPV); }

#if defined(__has_builtin)
#if __has_builtin(__builtin_amdgcn_fdot2)
#define DOT2(a,b,c) __builtin_amdgcn_fdot2((a),(b),(c),false)
#endif
#endif
#ifndef DOT2
#define DOT2(a,b,c) fmaf((float)(a).x,(float)(b).x, fmaf((float)(a).y,(float)(b).y,(c)))
#endif

#define DOT4Q(u, x) { \
    acc = DOT2(__builtin_bit_cast(h2_t,(x).x), __builtin_bit_cast(h2_t,(u).x), acc); \
    acc = DOT2(__builtin_bit_cast(h2_t,(x).y), __builtin_bit_cast(h2_t,(u).y), acc); \
    acc = DOT2(__builtin_bit_cast(h2_t,(x).z), __builtin_bit_cast(h2_t,(u).z), acc); \
    acc = DOT2(__builtin_bit_cast(h2_t,(x).w), __builtin_bit_cast(h2_t,(u).w), acc); }

__global__ void prep_kernel(const float* __restrict__ W_x, const float* __restrict__ W_h,
                            const float* __restrict__ W_p, const float* __restrict__ b_lstm,
                            const float* __restrict__ b_p,
                            h2_t* __restrict__ wxT, h2_t* __restrict__ whT,
                            h2_t* __restrict__ wpT,
                            float* __restrict__ blp, float* __restrict__ bpp)
{
    for (int idx = blockIdx.x*blockDim.x + threadIdx.x; idx < PREP_TOT; idx += gridDim.x*blockDim.x){
        if (idx < WXT_H2){
            // thread t, K-pair p; ctrl K-order: [r(0..63)->W_x row 9+k ; x(64..72)->row k-64 ; pad]
            int t = idx/40, p = idx - t*40;
            int u = t>>2, g = t&3, c = g*256 + u;
            int k0 = 2*p, k1 = 2*p+1;
            float f0 = (k0<64) ? W_x[(9+k0)*1024+c] : (k0<CTRL_ ? W_x[(k0-64)*1024+c] : 0.f);
            float f1 = (k1<64) ? W_x[(9+k1)*1024+c] : (k1<CTRL_ ? W_x[(k1-64)*1024+c] : 0.f);
            h2_t v; v.x = (_Float16)f0; v.y = (_Float16)f1;
            wxT[idx] = v;
        } else if (idx < WXT_H2 + WHT_H2){
            int e = idx - WXT_H2;
            int t = e>>7, p = e&127;
            int u = t>>2, g = t&3, c = g*256 + u;
            h2_t v; v.x = (_Float16)W_h[(2*p)*1024+c]; v.y = (_Float16)W_h[(2*p+1)*1024+c];
            whT[e] = v;
        } else if (idx < WXT_H2 + WHT_H2 + WPT_H2){
            int e = idx - WXT_H2 - WHT_H2;
            int tt = e>>6, i = e&63;
            int col = tt>>1, q = tt&1, p = q*64 + i;
            float f0 = (col<PP) ? W_p[(2*p)*PP + col] : 0.f;
            float f1 = (col<PP) ? W_p[(2*p+1)*PP + col] : 0.f;
            h2_t v; v.x = (_Float16)f0; v.y = (_Float16)f1;
            wpT[e] = v;
        } else if (idx < WXT_H2 + WHT_H2 + WPT_H2 + 1024){
            int jn = idx - (WXT_H2 + WHT_H2 + WPT_H2);
            int u = jn>>2, k = jn&3;
            blp[jn] = b_lstm[k*256 + u];
        } else {
            int j = idx - (WXT_H2 + WHT_H2 + WPT_H2 + 1024);
            bpp[j] = (j < PP) ? b_p[j] : 0.0f;
        }
    }
}

__global__ __launch_bounds__(1024,4) void ntm_kernel(
    const float* __restrict__ inputs,
    const float* __restrict__ W_o, const float* __restrict__ b_o,
    const float* __restrict__ r0, const float* __restrict__ w0,
    const h2_t* __restrict__ wxT, const h2_t* __restrict__ whT,
    const h2_t* __restrict__ wpT,
    const float* __restrict__ blp, const float* __restrict__ bpp,
    float* __restrict__ out)
{
    const int b = blockIdx.x;
    const int t = threadIdx.x;
    const int wv = t >> 6, ln = t & 63;

    __shared__ float Mem[NN][MM+1];
    __shared__ float hbuf[U_], cbuf[U_];
    __shared__ float4 gates4[U_];      // 1024 gates, unit-major
    __shared__ float gpart[4*U_];      // h@W_h + blp, one step ahead
    __shared__ float blpS[4*U_];
    __shared__ h2_t  xr2[40] __attribute__((aligned(16)));   // [r(32 pairs); x(5); pad(3)]
    __shared__ h2_t  hb2[U_/2] __attribute__((aligned(16))); // h as f16 pairs
    __shared__ float jpart[OUT_];
    __shared__ float kv[HH][MM];
    __shared__ float ebuf[MM], abuf[MM];
    __shared__ float prmS[12];
    __shared__ float scal[12];
    __shared__ float innr[HH][NN];
    __shared__ float Mn[NN];
    __shared__ float wgs[HH][NN];
    __shared__ float wtab[HH][NN];
    __shared__ float rpart[16][MM];

    _Float16* hbh = (_Float16*)hb2;
    float* gatesF = (float*)gates4;

    // ---- init ----
    for (int idx=t; idx<NN*MM; idx+=1024){ Mem[idx>>6][idx&63] = 1e-6f; }
    blpS[t] = blp[t];
    gpart[t] = blpS[t];
    if (t < NN) Mn[t] = sqrtf((float)MM * 1e-6f * 1e-6f);
    if (t < U_){ hbuf[t]=0.f; cbuf[t]=0.f; }
    if (t < U_/2){ h2_t z; z.x=(_Float16)0.f; z.y=(_Float16)0.f; hb2[t]=z; }
    if (t >= 256 && t < 296){
        int p = t-256;
        h2_t v;
        if (p < 32){ v.x = (_Float16)tanhf(r0[2*p]); v.y = (_Float16)tanhf(r0[2*p+1]); }
        else if (p < 37){
            int e0 = 2*(p-32), e1 = e0+1;
            float f0 = (e0<IN_DIM_) ? inputs[b*T_*IN_DIM_ + e0] : 0.f;
            float f1 = (e1<IN_DIM_) ? inputs[b*T_*IN_DIM_ + e1] : 0.f;
            v.x = (_Float16)f0; v.y = (_Float16)f1;
        } else { v.x=(_Float16)0.f; v.y=(_Float16)0.f; }
        xr2[p] = v;
    }
    if (t >= 128 && t < 256){  // wtab = softmax(w0)
        int h = (t-128)>>6, l = t&63;
        float v0 = w0[h*NN + l], v1 = w0[h*NN + l + 64];
        float mx = fmaxf(v0,v1);
        for (int off=32; off>=1; off>>=1) mx = fmaxf(mx, __shfl_xor(mx, off));
        float e0 = __expf(v0-mx), e1 = __expf(v1-mx);
        float s = e0+e1;
        for (int off=32; off>=1; off>>=1) s += __shfl_xor(s, off);
        wtab[h][l] = e0/s; wtab[h][l+64] = e1/s;
    }
    __syncthreads();

    for (int step=0; step<T_; ++step){
        // ---- B: gates[t] = ctrl . wxT[t][:] + gpart[t] (bias folded) ----
        {
            const uint4* wb = (const uint4*)((const char*)wxT + t*160);
            const uint4* xq = (const uint4*)xr2;
            float acc = 0.f;
            #pragma unroll 5
            for (int i=0; i<10; ++i){
                uint4 u = wb[i]; uint4 x = xq[i];
                DOT4Q(u, x);
            }
            gatesF[t] = acc + gpart[t];
        }
        __syncthreads();

        // ---- LSTM (unit u = t) ----
        if (t < U_){
            float4 g4 = gates4[t];
            float c = sigf(g4.y)*cbuf[t] + sigf(g4.x)*tanhf(g4.z);
            cbuf[t] = c;
            float h = sigf(g4.w)*tanhf(c);
            hbuf[t] = h; hbh[t] = (_Float16)h;
        }
        __syncthreads();

        // ---- FUSED: gpart (all threads) + params (t<544) + Mn/jpart/x-prefetch ----
        {
            const uint4* wb = (const uint4*)((const char*)whT + t*512);
            const uint4* hq = (const uint4*)hb2;
            float acc = 0.f;
            #pragma unroll 8
            for (int i=0; i<32; ++i){
                uint4 u = wb[i]; uint4 x = hq[i];
                DOT4Q(u, x);
            }
            gpart[t] = acc + blpS[t];
        }
        if (t < 544){
            const int col = t>>1, q = t&1;
            const uint4* wb = (const uint4*)((const char*)wpT + t*256);
            const uint4* hq = ((const uint4*)hb2) + q*16;
            float acc = 0.f;
            #pragma unroll 8
            for (int i=0; i<16; ++i){
                uint4 u = wb[i]; uint4 x = hq[i];
                DOT4Q(u, x);
            }
            float a = acc + __shfl_xor(acc, 1);
            if (q==0){
                float p = clipf(a + bpp[col]);
                if (col < 64) kv[0][col] = tanhf(p);
                else if (col < 70) prmS[col-64] = p;
                else if (col < 134) kv[1][col-70] = tanhf(p);
                else if (col < 140) prmS[6 + (col-134)] = p;
                else if (col < 204) ebuf[col-140] = sigf(p);
                else if (col < 268) abuf[col-204] = tanhf(p);
            }
        } else if (t < 800){
            const int idx = t-544, n = idx>>1, m0 = (idx&1)*32;
            float s = 0.f;
            #pragma unroll 8
            for (int m=m0; m<m0+32; ++m){ float v=Mem[n][m]; s=fmaf(v,v,s); }
            s += __shfl_xor(s,1);
            if ((idx&1)==0) Mn[n] = sqrtf(s);
        } else if (t < 805){
            if (step+1 < T_){
                const int p = t-800;
                const int e0 = 2*p, e1 = e0+1;
                const float* xin = inputs + (b*T_ + step+1)*IN_DIM_;
                h2_t v;
                v.x = (_Float16)((e0<IN_DIM_) ? xin[e0] : 0.f);
                v.y = (_Float16)((e1<IN_DIM_) ? xin[e1] : 0.f);
                xr2[32+p] = v;
            }
        } else if (t >= 896){
            const int o = (t-896)>>4, l16 = t&15;
            float s = 0.f;
            #pragma unroll
            for (int j=0; j<16; ++j){
                const int i = l16 + (j<<4);
                s = fmaf(hbuf[i], W_o[i*OUT_ + o], s);
            }
            s += __shfl_xor(s,1); s += __shfl_xor(s,2);
            s += __shfl_xor(s,4); s += __shfl_xor(s,8);
            if (l16==0) jpart[o] = s;
        }
        __syncthreads();

        // ---- F: inner products + scal decode ----
        {
            const int h = t>>9, n = (t>>2)&127, q = t&3, m0 = q*16;
            float s = 0.f;
            #pragma unroll 8
            for (int m=m0; m<m0+16; ++m) s = fmaf(kv[h][m], Mem[n][m], s);
            s += __shfl_xor(s,1); s += __shfl_xor(s,2);
            if (q==0) innr[h][n] = s;
        }
        if (t < 2){
            const int h = t;
            const float* ps = prmS + 6*h;
            scal[h]   = splus(ps[0]);
            scal[2+h] = sigf(ps[1]);
            float p0=ps[2], p1=ps[3], p2=ps[4];
            float mx = fmaxf(p0, fmaxf(p1, p2));
            float e0=__expf(p0-mx), e1=__expf(p1-mx), e2=__expf(p2-mx);
            float s = e0+e1+e2;
            scal[6+3*h]=e0/s; scal[7+3*h]=e1/s; scal[8+3*h]=e2/s;
            scal[4+h] = 1.f + splus(ps[5]);
        }
        __syncthreads();

        // ---- G: key norm + content softmax + interp + shift + sharpen ----
        if (t < 128){
            const int h = t>>6, l = ln;
            float kvl = kv[h][l];
            float kn2 = kvl*kvl;
            for (int off=32; off>=1; off>>=1) kn2 += __shfl_xor(kn2, off);
            float kn = sqrtf(kn2);
            float beta = scal[h], g = scal[2+h];
            float bk0 = beta * innr[h][l]   /(kn*Mn[l]   +1e-8f);
            float bk1 = beta * innr[h][l+64]/(kn*Mn[l+64]+1e-8f);
            float mx = fmaxf(bk0,bk1);
            for (int off=32; off>=1; off>>=1) mx = fmaxf(mx, __shfl_xor(mx, off));
            float e0=__expf(bk0-mx), e1=__expf(bk1-mx);
            float s=e0+e1;
            for (int off=32; off>=1; off>>=1) s += __shfl_xor(s, off);
            float wc0=e0/s, wc1=e1/s;
            wgs[h][l]    = g*wc0 + (1.f-g)*wtab[h][l];
            wgs[h][l+64] = g*wc1 + (1.f-g)*wtab[h][l+64];
            float gamma = scal[4+h];
            float s0=scal[6+3*h], s1=scal[7+3*h], s2=scal[8+3*h];
            const int n0=l, n1=l+64;
            float wt0 = s0*wgs[h][(n0+1)&127] + s1*wgs[h][n0] + s2*wgs[h][(n0+127)&127];
            float wt1 = s0*wgs[h][(n1+1)&127] + s1*wgs[h][n1] + s2*wgs[h][(n1+127)&127];
            float wp0 = __powf(wt0, gamma), wp1 = __powf(wt1, gamma);
            float ss = wp0+wp1;
            for (int off=32; off>=1; off>>=1) ss += __shfl_xor(ss, off);
            float inv = 1.0f/(ss+1e-8f);
            wtab[h][n0] = wp0*inv; wtab[h][n1] = wp1*inv;
        }
        __syncthreads();

        // ---- H: memory write + fused read-head partials ----
        {
            const float el = ebuf[ln], al = abuf[ln];
            const int n0 = wv*8;
            float racc = 0.f;
            #pragma unroll
            for (int k=0; k<8; ++k){
                const int n = n0+k;
                float ww = wtab[1][n];
                float wr = wtab[0][n];
                float v = Mem[n][ln]*(1.0f - ww*el) + ww*al;
                Mem[n][ln] = v;
                racc = fmaf(wr, v, racc);
            }
            rpart[wv][ln] = racc;
        }
        __syncthreads();

        // ---- J: r finalize + output ----
        if (t < 512){
            const int o = wv;
            float rm = 0.f;
            #pragma unroll
            for (int k=0; k<16; ++k) rm += rpart[k][ln];
            float s = rm * W_o[(U_+ln)*OUT_ + o];
            for (int off=32; off>=1; off>>=1) s += __shfl_xor(s, off);
            if (ln==0 && step>=TSTART){
                float logit = clipf(s + jpart[o] + b_o[o]);
                out[((b*(T_-TSTART)) + (step-TSTART))*OUT_ + o] = sigf(logit);
            }
        } else if (t < 576){
            float rm = 0.f;
            #pragma unroll
            for (int k=0; k<16; ++k) rm += rpart[k][ln];
            float other = __shfl_xor(rm, 1);
            if ((ln&1)==0){
                h2_t v; v.x = (_Float16)rm; v.y = (_Float16)other;
                xr2[ln>>1] = v;
            }
        }
        __syncthreads();
    }
}

extern "C" void kernel_launch(void* const* d_in, const int* in_sizes, int n_in,
                              void* d_out, int out_size, void* d_ws, size_t ws_size,
                              hipStream_t stream) {
    const float* inputs = (const float*)d_in[0];
    const float* W_x    = (const float*)d_in[1];
    const float* W_h    = (const float*)d_in[2];
    const float* b_lstm = (const float*)d_in[3];
    const float* W_p    = (const float*)d_in[4];
    const float* b_p    = (const float*)d_in[5];
    const float* W_o    = (const float*)d_in[6];
    const float* b_o    = (const float*)d_in[7];
    const float* r0     = (const float*)d_in[8];
    const float* w0     = (const float*)d_in[9];
    float* out = (float*)d_out;

    char* ws = (char*)d_ws;
    h2_t* wxT = (h2_t*)(ws + WXT_OFF);
    h2_t* whT = (h2_t*)(ws + WHT_OFF);
    h2_t* wpT = (h2_t*)(ws + WPT_OFF);
    float* blp = (float*)(ws + BLP_OFF);
    float* bpp = (float*)(ws + BPP_OFF);

    prep_kernel<<<512, 256, 0, stream>>>(W_x, W_h, W_p, b_lstm, b_p, wxT, whT, wpT, blp, bpp);
    ntm_kernel<<<B_, 1024, 0, stream>>>(inputs, W_o, b_o, r0, w0, wxT, whT, wpT, blp, bpp, out);
}

// Round 10
// 2279.157 us; speedup vs baseline: 4.5304x; 2.0705x over previous
//
#include <hip/hip_runtime.h>
#include <math.h>

typedef _Float16 h2_t __attribute__((ext_vector_type(2)));

#define U_ 256
#define NN 128
#define MM 64
#define OUT_ 8
#define CLIPV 20.0f
#define IN_DIM_ 9
#define PP 268
#define B_ 128
#define T_ 130
#define TSTART 65
#define CTRL_ 73

// ws layout (bytes). uint4 = 4 h2 = (2 K-rows) x (4 cols)
#define NWXG (2*128*41)     // [hf][g4(128)][slot(41: p*8+q, kk=q*5+p, slot40 pad)]
#define NWHG (2*128*128)    // [hf][g4][slot(128: p*8+q, kk=q*16+p)]
#define NWPG (2*34*128)     // [hf][cg(34)][slot(128)]
#define WXG_OFF 0
#define WXG_SZ  (NWXG*16)                 // 167936
#define WHG_OFF (WXG_OFF + WXG_SZ)        // 167936
#define WHG_SZ  (NWHG*16)                 // 524288
#define WPG_OFF (WHG_OFF + WHG_SZ)        // 692224
#define WPG_SZ  (NWPG*16)                 // 139264
#define BLH_OFF (WPG_OFF + WPG_SZ)        // 831488
#define BLH_SZ  (256*16)
#define BPP_OFF (BLH_OFF + BLH_SZ)        // 835584
#define BPP_SZ  (272*4)
#define COMM_OFF (BPP_OFF + BPP_SZ)       // 836672
#define COMM_STRIDE 2176                  // hA512|hB512|pA544|pB544|flags16|pad
#define COMM_SZ (B_*COMM_STRIDE)          // 278528
#define PREP_N  (NWXG + NWHG + NWPG + 256 + 272)

__device__ __forceinline__ float sigf(float x){ return 1.0f/(1.0f+__expf(-x)); }
__device__ __forceinline__ float splus(float x){ return log1pf(__expf(x)); }
__device__ __forceinline__ float clipf(float x){ return fminf(fmaxf(x,-CLIPV),CLIPV); }

#if defined(__has_builtin)
#if __has_builtin(__builtin_amdgcn_fdot2)
#define DOT2(a,b,c) __builtin_amdgcn_fdot2((a),(b),(c),false)
#endif
#endif
#ifndef DOT2
#define DOT2(a,b,c) fmaf((float)(a).x,(float)(b).x, fmaf((float)(a).y,(float)(b).y,(c)))
#endif

#define DOT2X4(uu, hv) { \
    a0 = DOT2(hv, __builtin_bit_cast(h2_t,(uu).x), a0); \
    a1 = DOT2(hv, __builtin_bit_cast(h2_t,(uu).y), a1); \
    a2 = DOT2(hv, __builtin_bit_cast(h2_t,(uu).z), a2); \
    a3 = DOT2(hv, __builtin_bit_cast(h2_t,(uu).w), a3); }

__device__ __forceinline__ unsigned packh2(float a, float b){
    h2_t v; v.x = (_Float16)a; v.y = (_Float16)b;
    return __builtin_bit_cast(unsigned, v);
}

__global__ void prep_kernel(const float* __restrict__ W_x, const float* __restrict__ W_h,
                            const float* __restrict__ W_p, const float* __restrict__ b_lstm,
                            const float* __restrict__ b_p,
                            uint4* __restrict__ wxg, uint4* __restrict__ whg,
                            uint4* __restrict__ wpg,
                            float4* __restrict__ blh, float* __restrict__ bpp)
{
    for (int idx = blockIdx.x*blockDim.x + threadIdx.x; idx < PREP_N; idx += gridDim.x*blockDim.x){
        if (idx < NWXG){
            int hf = idx/5248, rem = idx - hf*5248, g4 = rem/41, s = rem - g4*41;
            uint4 v = make_uint4(0,0,0,0);
            if (s < 40){
                int p = s>>3, q = s&7, kk = q*5+p, u = hf*128+g4;
                int k0 = 2*kk, k1 = 2*kk+1;
                unsigned c[4];
                #pragma unroll
                for (int g=0; g<4; ++g){
                    int col = g*256+u;
                    float f0 = (k0<64) ? W_x[(9+k0)*1024+col] : (k0<CTRL_ ? W_x[(k0-64)*1024+col] : 0.f);
                    float f1 = (k1<64) ? W_x[(9+k1)*1024+col] : (k1<CTRL_ ? W_x[(k1-64)*1024+col] : 0.f);
                    c[g] = packh2(f0,f1);
                }
                v = make_uint4(c[0],c[1],c[2],c[3]);
            }
            wxg[idx] = v;
        } else if (idx < NWXG + NWHG){
            int e = idx - NWXG;
            int hf = e/16384, rem = e - hf*16384, g4 = rem>>7, s = rem&127;
            int p = s>>3, q = s&7, kk = q*16+p, u = hf*128+g4;
            unsigned c[4];
            #pragma unroll
            for (int g=0; g<4; ++g){
                int col = g*256+u;
                c[g] = packh2(W_h[(2*kk)*1024+col], W_h[(2*kk+1)*1024+col]);
            }
            whg[e] = make_uint4(c[0],c[1],c[2],c[3]);
        } else if (idx < NWXG + NWHG + NWPG){
            int e = idx - NWXG - NWHG;
            int hf = e/4352, rem = e - hf*4352, cg = rem>>7, s = rem&127;
            int p = s>>3, q = s&7, kk = q*16+p;
            unsigned c[4];
            #pragma unroll
            for (int g=0; g<4; ++g){
                int cl = cg*4+g, rc = hf*134+cl;
                c[g] = (cl<134) ? packh2(W_p[(2*kk)*PP+rc], W_p[(2*kk+1)*PP+rc]) : 0u;
            }
            wpg[e] = make_uint4(c[0],c[1],c[2],c[3]);
        } else if (idx < NWXG + NWHG + NWPG + 256){
            int u = idx - NWXG - NWHG - NWPG;
            blh[u] = make_float4(b_lstm[u], b_lstm[256+u], b_lstm[512+u], b_lstm[768+u]);
        } else {
            int j = idx - NWXG - NWHG - NWPG - 256;
            bpp[j] = (j < PP) ? b_p[j] : 0.f;
        }
    }
}

__device__ __forceinline__ float decodeP(int rc, float p){
    if (rc < 64 || (rc >= 70 && rc < 134) || rc >= 204) return tanhf(p);
    if (rc >= 140 && rc < 204) return sigf(p);
    return p;  // raw scalars
}

__global__ __launch_bounds__(1024,1) void ntm_kernel(
    const float* __restrict__ inputs,
    const float* __restrict__ W_o, const float* __restrict__ b_o,
    const float* __restrict__ r0, const float* __restrict__ w0,
    const uint4* __restrict__ wxg, const uint4* __restrict__ whg,
    const uint4* __restrict__ wpg,
    const float4* __restrict__ blh, const float* __restrict__ bpp,
    char* comm, float* __restrict__ out)
{
    const int bid = blockIdx.x, hf = bid>>7, b = bid&127;
    const int t = threadIdx.x, wv = t>>6, ln = t&63;
    const int g4 = t>>3, q = t&7;

    char* cb = comm + b*COMM_STRIDE;
    volatile float* hOwn = (volatile float*)(cb + hf*512);
    volatile float* hOth = (volatile float*)(cb + (hf^1)*512);
    volatile float* pOwn = (volatile float*)(cb + 1024 + hf*544);
    volatile float* pOth = (volatile float*)(cb + 1024 + (hf^1)*544);
    volatile int*   flg  = (volatile int*)(cb + 2112);   // [f1A,f1B,f2A,f2B]

    __shared__ uint4 wxL[128*41];        // 84KB pinned W_x half
    __shared__ float Mem[NN][MM+1];
    __shared__ float4 gpart4[128];
    __shared__ float4 blhL[128];
    __shared__ float hbuf[U_];
    __shared__ float cbuf[128];
    __shared__ h2_t  hb2[128];
    __shared__ h2_t  xr2[40];
    __shared__ float prmS[12];
    __shared__ float scal[12];
    __shared__ float kv[2][MM], ebuf[MM], abuf[MM];
    __shared__ float innr[2][NN], Mn[NN], wgs[2][NN], wtab[2][NN];
    __shared__ float rpart[16][MM];
    __shared__ float jpart[OUT_];

    // ---- init ----
    for (int i=t; i<5248; i+=1024) wxL[i] = wxg[hf*5248 + i];
    for (int i=t; i<NN*MM; i+=1024) Mem[i>>6][i&63] = 1e-6f;
    if (t < 128){
        gpart4[t] = make_float4(0.f,0.f,0.f,0.f);
        blhL[t] = blh[hf*128+t];
        cbuf[t] = 0.f;
        Mn[t] = 8e-6f;
    }
    if (t < U_) hbuf[t] = 0.f;
    if (t >= 128 && t < 256){  // wtab = softmax(w0)
        int h = (t-128)>>6, l = t&63;
        float v0 = w0[h*NN + l], v1 = w0[h*NN + l + 64];
        float mx = fmaxf(v0,v1);
        for (int off=32; off>=1; off>>=1) mx = fmaxf(mx, __shfl_xor(mx, off));
        float e0 = __expf(v0-mx), e1 = __expf(v1-mx);
        float s = e0+e1;
        for (int off=32; off>=1; off>>=1) s += __shfl_xor(s, off);
        wtab[h][l] = e0/s; wtab[h][l+64] = e1/s;
    }
    if (t >= 256 && t < 296){
        int p = t-256;
        h2_t v;
        if (p < 32){ v.x = (_Float16)tanhf(r0[2*p]); v.y = (_Float16)tanhf(r0[2*p+1]); }
        else if (p < 37){
            int e0 = 2*(p-32), e1 = e0+1;
            float f0 = (e0<IN_DIM_) ? inputs[b*T_*IN_DIM_ + e0] : 0.f;
            float f1 = (e1<IN_DIM_) ? inputs[b*T_*IN_DIM_ + e1] : 0.f;
            v.x = (_Float16)f0; v.y = (_Float16)f1;
        } else { v.x=(_Float16)0.f; v.y=(_Float16)0.f; }
        xr2[p] = v;
    }
    __syncthreads();

    for (int step=0; step<T_; ++step){
        // ---- B: gates(own 512 cols) from LDS wx + gpart + bias, fused LSTM ----
        {
            const uint4* wrow = &wxL[g4*41];
            float a0=0.f,a1=0.f,a2=0.f,a3=0.f;
            #pragma unroll
            for (int p=0; p<5; ++p){
                uint4 u = wrow[p*8+q];
                h2_t xv = xr2[q*5+p];
                DOT2X4(u, xv);
            }
            #pragma unroll
            for (int m=1; m<8; m<<=1){
                a0 += __shfl_xor(a0,m); a1 += __shfl_xor(a1,m);
                a2 += __shfl_xor(a2,m); a3 += __shfl_xor(a3,m);
            }
            if (q==0){
                float4 bb = blhL[g4]; float4 gp = gpart4[g4];
                float gi=a0+bb.x+gp.x, gf=a1+bb.y+gp.y, gg=a2+bb.z+gp.z, go=a3+bb.w+gp.w;
                float c = sigf(gf)*cbuf[g4] + sigf(gi)*tanhf(gg);
                cbuf[g4] = c;
                float h = sigf(go)*tanhf(c);
                hbuf[hf*128+g4] = h;
                hOwn[g4] = h;                     // volatile -> MALL
            }
        }
        __syncthreads();                          // drains all volatile h stores
        if (t==0){
            flg[hf] = step+1;
            while (flg[hf^1] < step+1) __builtin_amdgcn_s_sleep(8);
        }
        __syncthreads();
        // pull partner h; build fp16 h pairs
        if (t < 128){
            float hv = hOth[t];
            hbuf[(hf^1)*128 + t] = hv;
            float hv2 = __shfl_down(hv, 1);
            if (!(t&1)){ h2_t vv; vv.x=(_Float16)hv; vv.y=(_Float16)hv2; hb2[(hf^1)*64 + (t>>1)] = vv; }
        } else if (t < 192){
            int jj = t-128;   // own half pairs
            h2_t vv; vv.x=(_Float16)hbuf[hf*128+2*jj]; vv.y=(_Float16)hbuf[hf*128+2*jj+1];
            hb2[hf*64+jj] = vv;
        }
        __syncthreads();

        // ---- FUSED: gpart (all) ; wp+decode (272) ; Mn (256) ; jpart (128) ; x-pre ----
        {
            const uint4* wrow = whg + hf*16384 + g4*128;
            float a0=0.f,a1=0.f,a2=0.f,a3=0.f;
            #pragma unroll 4
            for (int p=0; p<16; ++p){
                uint4 u = wrow[p*8+q];
                h2_t hv = hb2[q*16+p];
                DOT2X4(u, hv);
            }
            #pragma unroll
            for (int m=1; m<8; m<<=1){
                a0 += __shfl_xor(a0,m); a1 += __shfl_xor(a1,m);
                a2 += __shfl_xor(a2,m); a3 += __shfl_xor(a3,m);
            }
            if (q==0) gpart4[g4] = make_float4(a0,a1,a2,a3);
        }
        if (t < 272){
            const int cg = t>>3, qq = t&7;
            const uint4* wrow = wpg + (hf*34+cg)*128;
            float a0=0.f,a1=0.f,a2=0.f,a3=0.f;
            #pragma unroll 4
            for (int p=0; p<16; ++p){
                uint4 u = wrow[p*8+qq];
                h2_t hv = hb2[qq*16+p];
                DOT2X4(u, hv);
            }
            #pragma unroll
            for (int m=1; m<8; m<<=1){
                a0 += __shfl_xor(a0,m); a1 += __shfl_xor(a1,m);
                a2 += __shfl_xor(a2,m); a3 += __shfl_xor(a3,m);
            }
            if (qq==0){
                float av0=a0, av1=a1, av2=a2, av3=a3;
                #pragma unroll
                for (int j=0; j<4; ++j){
                    float aj = (j==0)?av0:((j==1)?av1:((j==2)?av2:av3));
                    int cl = cg*4+j;
                    if (cl < 134){
                        int rc = hf*134+cl;
                        float pv = clipf(aj + bpp[rc]);
                        float dv = decodeP(rc, pv);
                        pOwn[cl] = dv;
                        if (rc < 64) kv[0][rc] = dv;
                        else if (rc < 70) prmS[rc-64] = dv;
                        else if (rc < 134) kv[1][rc-70] = dv;
                        else if (rc < 140) prmS[6+rc-134] = dv;
                        else if (rc < 204) ebuf[rc-140] = dv;
                        else abuf[rc-204] = dv;
                    }
                }
            }
        } else if (t < 528){
            const int idx = t-272, n = idx>>1, m0 = (idx&1)*32;
            float s = 0.f;
            #pragma unroll 8
            for (int m=m0; m<m0+32; ++m){ float v=Mem[n][m]; s=fmaf(v,v,s); }
            s += __shfl_xor(s,1);
            if (!(idx&1)) Mn[n] = sqrtf(s);
        } else if (t < 656){
            const int o = (t-528)>>4, l16 = (t-528)&15;
            float s = 0.f;
            #pragma unroll
            for (int j=0; j<16; ++j){
                const int i = l16 + (j<<4);
                s = fmaf(hbuf[i], W_o[i*OUT_ + o], s);
            }
            s += __shfl_xor(s,1); s += __shfl_xor(s,2);
            s += __shfl_xor(s,4); s += __shfl_xor(s,8);
            if (l16==0) jpart[o] = s;
        } else if (t >= 656 && t < 661){
            if (step+1 < T_){
                const int p = t-656;
                const int e0 = 2*p, e1 = e0+1;
                const float* xin = inputs + (b*T_ + step+1)*IN_DIM_;
                h2_t v;
                v.x = (_Float16)((e0<IN_DIM_) ? xin[e0] : 0.f);
                v.y = (_Float16)((e1<IN_DIM_) ? xin[e1] : 0.f);
                xr2[32+p] = v;
            }
        }
        __syncthreads();                          // drains volatile p stores
        if (t==0){
            flg[2+hf] = step+1;
            while (flg[2+(hf^1)] < step+1) __builtin_amdgcn_s_sleep(8);
        }
        __syncthreads();
        if (t < 134){                              // route partner's decoded params
            float dv = pOth[t];
            int rc = (hf^1)*134 + t;
            if (rc < 64) kv[0][rc] = dv;
            else if (rc < 70) prmS[rc-64] = dv;
            else if (rc < 134) kv[1][rc-70] = dv;
            else if (rc < 140) prmS[6+rc-134] = dv;
            else if (rc < 204) ebuf[rc-140] = dv;
            else abuf[rc-204] = dv;
        }
        __syncthreads();

        // ---- F: inner products + scal decode ----
        {
            const int h = t>>9, n = (t>>2)&127, qm = t&3, m0 = qm*16;
            float s = 0.f;
            #pragma unroll 8
            for (int m=m0; m<m0+16; ++m) s = fmaf(kv[h][m], Mem[n][m], s);
            s += __shfl_xor(s,1); s += __shfl_xor(s,2);
            if (qm==0) innr[h][n] = s;
        }
        if (t < 2){
            const int h = t;
            const float* ps = prmS + 6*h;
            scal[h]   = splus(ps[0]);
            scal[2+h] = sigf(ps[1]);
            float p0=ps[2], p1=ps[3], p2=ps[4];
            float mx = fmaxf(p0, fmaxf(p1, p2));
            float e0=__expf(p0-mx), e1=__expf(p1-mx), e2=__expf(p2-mx);
            float s = e0+e1+e2;
            scal[6+3*h]=e0/s; scal[7+3*h]=e1/s; scal[8+3*h]=e2/s;
            scal[4+h] = 1.f + splus(ps[5]);
        }
        __syncthreads();

        // ---- G: key norm + content softmax + interp + shift + sharpen ----
        if (t < 128){
            const int h = t>>6, l = ln;
            float kvl = kv[h][l];
            float kn2 = kvl*kvl;
            for (int off=32; off>=1; off>>=1) kn2 += __shfl_xor(kn2, off);
            float kn = sqrtf(kn2);
            float beta = scal[h], g = scal[2+h];
            float bk0 = beta * innr[h][l]   /(kn*Mn[l]   +1e-8f);
            float bk1 = beta * innr[h][l+64]/(kn*Mn[l+64]+1e-8f);
            float mx = fmaxf(bk0,bk1);
            for (int off=32; off>=1; off>>=1) mx = fmaxf(mx, __shfl_xor(mx, off));
            float e0=__expf(bk0-mx), e1=__expf(bk1-mx);
            float s=e0+e1;
            for (int off=32; off>=1; off>>=1) s += __shfl_xor(s, off);
            float wc0=e0/s, wc1=e1/s;
            wgs[h][l]    = g*wc0 + (1.f-g)*wtab[h][l];
            wgs[h][l+64] = g*wc1 + (1.f-g)*wtab[h][l+64];
            float gamma = scal[4+h];
            float s0=scal[6+3*h], s1=scal[7+3*h], s2=scal[8+3*h];
            const int n0=l, n1=l+64;
            float wt0 = s0*wgs[h][(n0+1)&127] + s1*wgs[h][n0] + s2*wgs[h][(n0+127)&127];
            float wt1 = s0*wgs[h][(n1+1)&127] + s1*wgs[h][n1] + s2*wgs[h][(n1+127)&127];
            float wp0 = __powf(wt0, gamma), wp1 = __powf(wt1, gamma);
            float ss = wp0+wp1;
            for (int off=32; off>=1; off>>=1) ss += __shfl_xor(ss, off);
            float inv = 1.0f/(ss+1e-8f);
            wtab[h][n0] = wp0*inv; wtab[h][n1] = wp1*inv;
        }
        __syncthreads();

        // ---- H: memory write + fused read-head partials ----
        {
            const float el = ebuf[ln], al = abuf[ln];
            const int n0 = wv*8;
            float racc = 0.f;
            #pragma unroll
            for (int k=0; k<8; ++k){
                const int n = n0+k;
                float ww = wtab[1][n];
                float wr = wtab[0][n];
                float v = Mem[n][ln]*(1.0f - ww*el) + ww*al;
                Mem[n][ln] = v;
                racc = fmaf(wr, v, racc);
            }
            rpart[wv][ln] = racc;
        }
        __syncthreads();

        // ---- J: r finalize + output (hf==0 writes) + xr2 r-pack ----
        if (t < 512){
            const int o = wv;
            float rm = 0.f;
            #pragma unroll
            for (int k=0; k<16; ++k) rm += rpart[k][ln];
            float s = rm * W_o[(U_+ln)*OUT_ + o];
            for (int off=32; off>=1; off>>=1) s += __shfl_xor(s, off);
            if (ln==0 && hf==0 && step>=TSTART){
                float logit = clipf(s + jpart[o] + b_o[o]);
                out[((b*(T_-TSTART)) + (step-TSTART))*OUT_ + o] = sigf(logit);
            }
        } else if (t < 576){
            float rm = 0.f;
            #pragma unroll
            for (int k=0; k<16; ++k) rm += rpart[k][ln];
            float other = __shfl_xor(rm, 1);
            if (!(ln&1)){
                h2_t v; v.x = (_Float16)rm; v.y = (_Float16)other;
                xr2[ln>>1] = v;
            }
        }
        __syncthreads();
    }
}

extern "C" void kernel_launch(void* const* d_in, const int* in_sizes, int n_in,
                              void* d_out, int out_size, void* d_ws, size_t ws_size,
                              hipStream_t stream) {
    const float* inputs = (const float*)d_in[0];
    const float* W_x    = (const float*)d_in[1];
    const float* W_h    = (const float*)d_in[2];
    const float* b_lstm = (const float*)d_in[3];
    const float* W_p    = (const float*)d_in[4];
    const float* b_p    = (const float*)d_in[5];
    const float* W_o    = (const float*)d_in[6];
    const float* b_o    = (const float*)d_in[7];
    const float* r0     = (const float*)d_in[8];
    const float* w0     = (const float*)d_in[9];
    float* out = (float*)d_out;

    char* ws = (char*)d_ws;
    uint4*  wxg = (uint4*)(ws + WXG_OFF);
    uint4*  whg = (uint4*)(ws + WHG_OFF);
    uint4*  wpg = (uint4*)(ws + WPG_OFF);
    float4* blh = (float4*)(ws + BLH_OFF);
    float*  bpp = (float*)(ws + BPP_OFF);
    char*   comm = ws + COMM_OFF;

    hipMemsetAsync(comm, 0, COMM_SZ, stream);   // fresh flags every launch/replay
    prep_kernel<<<512, 256, 0, stream>>>(W_x, W_h, W_p, b_lstm, b_p, wxg, whg, wpg, blh, bpp);
    ntm_kernel<<<2*B_, 1024, 0, stream>>>(inputs, W_o, b_o, r0, w0,
                                          wxg, whg, wpg, blh, bpp, comm, out);
}